// Round 1
// baseline (1705.480 us; speedup 1.0000x reference)
//
#include <hip/hip_runtime.h>
#include <hip/hip_bf16.h>
#include <cstddef>

#define T_ 4
#define B_ 16
#define N_ 512
#define C_ 512
#define H_ 8
#define D_ 64
#define BN_T (B_*N_)   // 8192

typedef unsigned short u16;

__device__ __forceinline__ float bf2f(u16 u) {
    union { unsigned int i; float f; } x; x.i = ((unsigned int)u) << 16; return x.f;
}

// Fused Linear (y = x @ W^T + b) -> BatchNorm(eval) -> LIF(v_th=1.0) over T=4.
// Each block computes a 64x64 (row=b*N+n, col=c) tile for ALL 4 timesteps so the
// LIF recurrence runs in registers. Output: HEAD_OUT -> bf16 spikes [T,B,H,N,D];
// else -> fp32 spikes [T,B,N,C] (the final d_out).
template<bool BF16_IN, bool HEAD_OUT>
__global__ __launch_bounds__(256) void k_linear_bn_lif(
    const void* __restrict__ xin, const float* __restrict__ w,
    const float* __restrict__ bias, const float* __restrict__ gamma,
    const float* __restrict__ beta, const float* __restrict__ mean,
    const float* __restrict__ var, void* __restrict__ outp)
{
    __shared__ float xs[T_][32][68];   // [t][k][row], transposed for b128 reads
    __shared__ float wt[32][68];       // [k][col]
    const int tid = threadIdx.x;
    const int c0 = blockIdx.x * 64;
    const int r0 = blockIdx.y * 64;
    const int tr = (tid >> 4) << 2;    // local row base (0..60)
    const int tc = (tid & 15) << 2;    // local col base (0..60)

    float acc[T_][4][4];
    #pragma unroll
    for (int t = 0; t < T_; ++t)
        #pragma unroll
        for (int i = 0; i < 4; ++i)
            #pragma unroll
            for (int j = 0; j < 4; ++j) acc[t][i][j] = 0.f;

    #pragma unroll 1
    for (int kb = 0; kb < C_ / 32; ++kb) {
        const int k0 = kb * 32;
        __syncthreads();
        // stage W tile: w[c0+col][k0+k] -> wt[k][col]
        #pragma unroll
        for (int i = 0; i < 2; ++i) {
            const int v = tid + i * 256;
            const int col = v >> 3, kq = (v & 7) << 2;
            const float4 f = *reinterpret_cast<const float4*>(w + (size_t)(c0 + col) * C_ + k0 + kq);
            wt[kq + 0][col] = f.x; wt[kq + 1][col] = f.y;
            wt[kq + 2][col] = f.z; wt[kq + 3][col] = f.w;
        }
        // stage x tiles for all 4 t
        #pragma unroll
        for (int t = 0; t < T_; ++t) {
            #pragma unroll
            for (int i = 0; i < 2; ++i) {
                const int v = tid + i * 256;
                const int row = v >> 3, kq = (v & 7) << 2;
                const size_t g = ((size_t)t * BN_T + r0 + row) * C_ + k0 + kq;
                float f0, f1, f2, f3;
                if (BF16_IN) {
                    const ushort4 u = *reinterpret_cast<const ushort4*>((const u16*)xin + g);
                    f0 = bf2f(u.x); f1 = bf2f(u.y); f2 = bf2f(u.z); f3 = bf2f(u.w);
                } else {
                    const float4 f = *reinterpret_cast<const float4*>((const float*)xin + g);
                    f0 = f.x; f1 = f.y; f2 = f.z; f3 = f.w;
                }
                xs[t][kq + 0][row] = f0; xs[t][kq + 1][row] = f1;
                xs[t][kq + 2][row] = f2; xs[t][kq + 3][row] = f3;
            }
        }
        __syncthreads();
        #pragma unroll
        for (int k = 0; k < 32; ++k) {
            const float4 wv4 = *reinterpret_cast<const float4*>(&wt[k][tc]);
            const float wv[4] = {wv4.x, wv4.y, wv4.z, wv4.w};
            #pragma unroll
            for (int t = 0; t < T_; ++t) {
                const float4 xv4 = *reinterpret_cast<const float4*>(&xs[t][k][tr]);
                const float xv[4] = {xv4.x, xv4.y, xv4.z, xv4.w};
                #pragma unroll
                for (int i = 0; i < 4; ++i)
                    #pragma unroll
                    for (int j = 0; j < 4; ++j)
                        acc[t][i][j] = fmaf(xv[i], wv[j], acc[t][i][j]);
            }
        }
    }

    // epilogue: bias -> BN(eval, reference op order) -> LIF(v_th=1) over t
    #pragma unroll
    for (int j = 0; j < 4; ++j) {
        const int c = c0 + tc + j;
        const float rs = 1.0f / sqrtf(var[c] + 1e-5f);
        const float ga = gamma[c], be = beta[c], mu = mean[c], bi = bias[c];
        #pragma unroll
        for (int i = 0; i < 4; ++i) {
            const int r = r0 + tr + i;
            float vm = 0.f;
            #pragma unroll
            for (int t = 0; t < T_; ++t) {
                const float y = acc[t][i][j] + bi;
                const float ybn = (y - mu) * rs * ga + be;
                const float h = vm + (ybn - vm) * 0.5f;   // v + (x - v)/TAU, TAU=2
                const bool sp = (h >= 1.0f);
                vm = sp ? 0.f : h;                        // hard reset
                if (HEAD_OUT) {
                    const int b = r >> 9, n = r & (N_ - 1);
                    const int hh = c >> 6, d = c & (D_ - 1);
                    const size_t oi = ((((size_t)t * B_ + b) * H_ + hh) * N_ + n) * D_ + d;
                    ((u16*)outp)[oi] = sp ? 0x3F80 : 0;   // bf16 1.0 / 0.0
                } else {
                    const size_t oi = ((size_t)t * BN_T + r) * C_ + c;
                    ((float*)outp)[oi] = sp ? 1.0f : 0.0f;
                }
            }
        }
    }
}

// Fused attention O = (Q K^T * 0.125) V per (t,b,h) + LIF(v_th=0.5) across t.
// Block owns (b,h, 64 Q-rows); loops t with membrane state in registers.
// All arithmetic here is EXACT (binary spikes -> integer dot products).
__global__ __launch_bounds__(256) void k_attn_lif(
    const u16* __restrict__ qg, const u16* __restrict__ kg,
    const u16* __restrict__ vg, u16* __restrict__ s2)
{
    __shared__ float qs[D_][68];   // [d][r]
    __shared__ float ks[D_][68];   // [d][m]
    __shared__ float ss[64][68];   // [m][r]  (scaled scores)
    __shared__ u16  vs[64][68];    // [m][d]  (bf16 spikes)
    const int tid = threadIdx.x;
    const int n0 = blockIdx.x * 64;
    const int bh = blockIdx.y;     // b*H + h
    const int tr = (tid >> 4) << 2;
    const int tc = (tid & 15) << 2;
    const int b = bh >> 3, hh = bh & 7;

    float vmem[4][4];
    #pragma unroll
    for (int i = 0; i < 4; ++i)
        #pragma unroll
        for (int j = 0; j < 4; ++j) vmem[i][j] = 0.f;

    #pragma unroll 1
    for (int t = 0; t < T_; ++t) {
        const size_t base = ((size_t)t * (B_ * H_) + bh) * (size_t)(N_ * D_);
        __syncthreads();
        // stage Q tile -> qs[d][r]
        #pragma unroll
        for (int i = 0; i < 4; ++i) {
            const int vv = tid + i * 256;
            const int row = vv >> 4, dq = (vv & 15) << 2;
            const ushort4 u = *reinterpret_cast<const ushort4*>(qg + base + (size_t)(n0 + row) * D_ + dq);
            qs[dq + 0][row] = bf2f(u.x); qs[dq + 1][row] = bf2f(u.y);
            qs[dq + 2][row] = bf2f(u.z); qs[dq + 3][row] = bf2f(u.w);
        }
        float o[4][4];
        #pragma unroll
        for (int i = 0; i < 4; ++i)
            #pragma unroll
            for (int j = 0; j < 4; ++j) o[i][j] = 0.f;

        #pragma unroll 1
        for (int jt = 0; jt < N_ / 64; ++jt) {
            const int m0 = jt * 64;
            __syncthreads();
            // stage K (transposed) and V tiles
            #pragma unroll
            for (int i = 0; i < 4; ++i) {
                const int vv = tid + i * 256;
                const int row = vv >> 4, dq = (vv & 15) << 2;
                const ushort4 u = *reinterpret_cast<const ushort4*>(kg + base + (size_t)(m0 + row) * D_ + dq);
                ks[dq + 0][row] = bf2f(u.x); ks[dq + 1][row] = bf2f(u.y);
                ks[dq + 2][row] = bf2f(u.z); ks[dq + 3][row] = bf2f(u.w);
                *reinterpret_cast<ushort4*>(&vs[row][dq]) =
                    *reinterpret_cast<const ushort4*>(vg + base + (size_t)(m0 + row) * D_ + dq);
            }
            __syncthreads();
            // S = Q K^T (exact integers), thread -> 4 rows x 4 m-cols
            float sa[4][4];
            #pragma unroll
            for (int i = 0; i < 4; ++i)
                #pragma unroll
                for (int j = 0; j < 4; ++j) sa[i][j] = 0.f;
            #pragma unroll
            for (int d = 0; d < D_; ++d) {
                const float4 qv4 = *reinterpret_cast<const float4*>(&qs[d][tr]);
                const float4 kv4 = *reinterpret_cast<const float4*>(&ks[d][tc]);
                const float qv[4] = {qv4.x, qv4.y, qv4.z, qv4.w};
                const float kv[4] = {kv4.x, kv4.y, kv4.z, kv4.w};
                #pragma unroll
                for (int i = 0; i < 4; ++i)
                    #pragma unroll
                    for (int j = 0; j < 4; ++j)
                        sa[i][j] = fmaf(qv[i], kv[j], sa[i][j]);
            }
            #pragma unroll
            for (int j = 0; j < 4; ++j)
                #pragma unroll
                for (int i = 0; i < 4; ++i)
                    ss[tc + j][tr + i] = sa[i][j] * 0.125f;   // exact scale
            __syncthreads();
            // O += S V, thread -> 4 rows x 4 d-cols
            #pragma unroll
            for (int m = 0; m < 64; ++m) {
                const float4 sv4 = *reinterpret_cast<const float4*>(&ss[m][tr]);
                const ushort4 uv = *reinterpret_cast<const ushort4*>(&vs[m][tc]);
                const float sv[4] = {sv4.x, sv4.y, sv4.z, sv4.w};
                const float vv[4] = {bf2f(uv.x), bf2f(uv.y), bf2f(uv.z), bf2f(uv.w)};
                #pragma unroll
                for (int i = 0; i < 4; ++i)
                    #pragma unroll
                    for (int j = 0; j < 4; ++j)
                        o[i][j] = fmaf(sv[i], vv[j], o[i][j]);
            }
        }
        // LIF(v_th=0.5), exact; write spikes to [T,B,N,C] as bf16
        #pragma unroll
        for (int i = 0; i < 4; ++i) {
            const int n = n0 + tr + i;
            #pragma unroll
            for (int j = 0; j < 4; ++j) {
                const int c = hh * D_ + tc + j;
                const float h = vmem[i][j] + (o[i][j] - vmem[i][j]) * 0.5f;
                const bool sp = (h >= 0.5f);
                vmem[i][j] = sp ? 0.f : h;
                const size_t oi = ((size_t)t * BN_T + (size_t)b * N_ + n) * C_ + c;
                s2[oi] = sp ? 0x3F80 : 0;
            }
        }
    }
}

extern "C" void kernel_launch(void* const* d_in, const int* in_sizes, int n_in,
                              void* d_out, int out_size, void* d_ws, size_t ws_size,
                              hipStream_t stream)
{
    const float* x = (const float*)d_in[0];
    // order per setup_inputs: for p in qkvp: w,b,gamma,beta,mean,var
    const float* W[4]  = {(const float*)d_in[1],  (const float*)d_in[7],  (const float*)d_in[13], (const float*)d_in[19]};
    const float* Bi[4] = {(const float*)d_in[2],  (const float*)d_in[8],  (const float*)d_in[14], (const float*)d_in[20]};
    const float* Ga[4] = {(const float*)d_in[3],  (const float*)d_in[9],  (const float*)d_in[15], (const float*)d_in[21]};
    const float* Be[4] = {(const float*)d_in[4],  (const float*)d_in[10], (const float*)d_in[16], (const float*)d_in[22]};
    const float* Mu[4] = {(const float*)d_in[5],  (const float*)d_in[11], (const float*)d_in[17], (const float*)d_in[23]};
    const float* Va[4] = {(const float*)d_in[6],  (const float*)d_in[12], (const float*)d_in[18], (const float*)d_in[24]};

    const size_t SPK = (size_t)T_ * B_ * N_ * C_;   // 16,777,216 elems
    u16* qb  = (u16*)d_ws;          // bf16 spikes [T,B,H,N,D]
    u16* kbf = qb + SPK;
    u16* vbf = kbf + SPK;
    u16* s2  = vbf + SPK;           // bf16 spikes [T,B,N,C]

    dim3 grid(C_ / 64, BN_T / 64), blk(256);
    k_linear_bn_lif<false, true><<<grid, blk, 0, stream>>>(x, W[0], Bi[0], Ga[0], Be[0], Mu[0], Va[0], qb);
    k_linear_bn_lif<false, true><<<grid, blk, 0, stream>>>(x, W[1], Bi[1], Ga[1], Be[1], Mu[1], Va[1], kbf);
    k_linear_bn_lif<false, true><<<grid, blk, 0, stream>>>(x, W[2], Bi[2], Ga[2], Be[2], Mu[2], Va[2], vbf);
    k_attn_lif<<<dim3(N_ / 64, B_ * H_), blk, 0, stream>>>(qb, kbf, vbf, s2);
    k_linear_bn_lif<true, false><<<grid, blk, 0, stream>>>(s2, W[3], Bi[3], Ga[3], Be[3], Mu[3], Va[3], d_out);
}

// Round 2
// 1041.662 us; speedup vs baseline: 1.6373x; 1.6373x over previous
//
#include <hip/hip_runtime.h>
#include <hip/hip_bf16.h>
#include <cstddef>

#define T_ 4
#define B_ 16
#define N_ 512
#define C_ 512
#define H_ 8
#define D_ 64
#define BN_T (B_*N_)   // 8192

typedef unsigned short u16;
typedef __attribute__((ext_vector_type(8))) short bf16x8;   // 8 bf16 (4 VGPRs)
typedef __attribute__((ext_vector_type(4))) float f32x4;

__device__ __forceinline__ float bf2f(u16 u) {
    union { unsigned int i; float f; } x; x.i = ((unsigned int)u) << 16; return x.f;
}
__device__ __forceinline__ u16 f2bf_exact(float f) {
    // value is an exact bf16 (multiple of 1/8, <= 8) -> truncation is exact
    union { float f; unsigned u; } x; x.f = f; return (u16)(x.u >> 16);
}
// XOR swizzle for 64-col u16 row-major tiles (stride 128B): spreads the
// stride-128B fragment reads across all banks. Element-index form.
__device__ __forceinline__ int SW(int row, int col) {
    return (row << 6) + (col ^ ((row & 7) << 3));
}

// ---------------------------------------------------------------------------
// Fused Linear (y = x @ W^T + b) -> BatchNorm(eval) -> LIF(v_th=1.0) over T=4.
// (unchanged from round 1 — numerically sensitive, keep fp32 VALU)
// ---------------------------------------------------------------------------
template<bool BF16_IN, bool HEAD_OUT>
__global__ __launch_bounds__(256) void k_linear_bn_lif(
    const void* __restrict__ xin, const float* __restrict__ w,
    const float* __restrict__ bias, const float* __restrict__ gamma,
    const float* __restrict__ beta, const float* __restrict__ mean,
    const float* __restrict__ var, void* __restrict__ outp)
{
    __shared__ float xs[T_][32][68];   // [t][k][row], transposed for b128 reads
    __shared__ float wt[32][68];       // [k][col]
    const int tid = threadIdx.x;
    const int c0 = blockIdx.x * 64;
    const int r0 = blockIdx.y * 64;
    const int tr = (tid >> 4) << 2;    // local row base (0..60)
    const int tc = (tid & 15) << 2;    // local col base (0..60)

    float acc[T_][4][4];
    #pragma unroll
    for (int t = 0; t < T_; ++t)
        #pragma unroll
        for (int i = 0; i < 4; ++i)
            #pragma unroll
            for (int j = 0; j < 4; ++j) acc[t][i][j] = 0.f;

    #pragma unroll 1
    for (int kb = 0; kb < C_ / 32; ++kb) {
        const int k0 = kb * 32;
        __syncthreads();
        #pragma unroll
        for (int i = 0; i < 2; ++i) {
            const int v = tid + i * 256;
            const int col = v >> 3, kq = (v & 7) << 2;
            const float4 f = *reinterpret_cast<const float4*>(w + (size_t)(c0 + col) * C_ + k0 + kq);
            wt[kq + 0][col] = f.x; wt[kq + 1][col] = f.y;
            wt[kq + 2][col] = f.z; wt[kq + 3][col] = f.w;
        }
        #pragma unroll
        for (int t = 0; t < T_; ++t) {
            #pragma unroll
            for (int i = 0; i < 2; ++i) {
                const int v = tid + i * 256;
                const int row = v >> 3, kq = (v & 7) << 2;
                const size_t g = ((size_t)t * BN_T + r0 + row) * C_ + k0 + kq;
                float f0, f1, f2, f3;
                if (BF16_IN) {
                    const ushort4 u = *reinterpret_cast<const ushort4*>((const u16*)xin + g);
                    f0 = bf2f(u.x); f1 = bf2f(u.y); f2 = bf2f(u.z); f3 = bf2f(u.w);
                } else {
                    const float4 f = *reinterpret_cast<const float4*>((const float*)xin + g);
                    f0 = f.x; f1 = f.y; f2 = f.z; f3 = f.w;
                }
                xs[t][kq + 0][row] = f0; xs[t][kq + 1][row] = f1;
                xs[t][kq + 2][row] = f2; xs[t][kq + 3][row] = f3;
            }
        }
        __syncthreads();
        #pragma unroll
        for (int k = 0; k < 32; ++k) {
            const float4 wv4 = *reinterpret_cast<const float4*>(&wt[k][tc]);
            const float wv[4] = {wv4.x, wv4.y, wv4.z, wv4.w};
            #pragma unroll
            for (int t = 0; t < T_; ++t) {
                const float4 xv4 = *reinterpret_cast<const float4*>(&xs[t][k][tr]);
                const float xv[4] = {xv4.x, xv4.y, xv4.z, xv4.w};
                #pragma unroll
                for (int i = 0; i < 4; ++i)
                    #pragma unroll
                    for (int j = 0; j < 4; ++j)
                        acc[t][i][j] = fmaf(xv[i], wv[j], acc[t][i][j]);
            }
        }
    }

    #pragma unroll
    for (int j = 0; j < 4; ++j) {
        const int c = c0 + tc + j;
        const float rs = 1.0f / sqrtf(var[c] + 1e-5f);
        const float ga = gamma[c], be = beta[c], mu = mean[c], bi = bias[c];
        #pragma unroll
        for (int i = 0; i < 4; ++i) {
            const int r = r0 + tr + i;
            float vm = 0.f;
            #pragma unroll
            for (int t = 0; t < T_; ++t) {
                const float y = acc[t][i][j] + bi;
                const float ybn = (y - mu) * rs * ga + be;
                const float h = vm + (ybn - vm) * 0.5f;   // v + (x - v)/TAU, TAU=2
                const bool sp = (h >= 1.0f);
                vm = sp ? 0.f : h;                        // hard reset
                if (HEAD_OUT) {
                    const int b = r >> 9, n = r & (N_ - 1);
                    const int hh = c >> 6, d = c & (D_ - 1);
                    const size_t oi = ((((size_t)t * B_ + b) * H_ + hh) * N_ + n) * D_ + d;
                    ((u16*)outp)[oi] = sp ? 0x3F80 : 0;   // bf16 1.0 / 0.0
                } else {
                    const size_t oi = ((size_t)t * BN_T + r) * C_ + c;
                    ((float*)outp)[oi] = sp ? 1.0f : 0.0f;
                }
            }
        }
    }
}

// ---------------------------------------------------------------------------
// MFMA attention: O = (Q K^T * 0.125) V per (t,b,h) + LIF(v_th=0.5) across t.
// All arithmetic EXACT (binary spikes; S is a multiple of 1/8 <= 8, exact in
// bf16; PV accumulates multiples of 1/8 bounded by 4096 -> exact in fp32).
// Block = (b, h, 64 q-rows); 4 waves, each owns a 16-row q strip; loop t with
// LIF membrane state in registers.
// Fragment layouts (mfma_f32_16x16x32_bf16):
//   A: lane l holds A[l&15][8*(l>>4)+i], i=0..7 (contiguous k -> b128 loads)
//   B: lane l holds B[8*(l>>4)+i][l&15]
//   C/D: lane l, reg r -> [ (l>>4)*4 + r ][ l&15 ]   (m89-verified)
// ---------------------------------------------------------------------------
__global__ __launch_bounds__(256) void k_attn_mfma(
    const u16* __restrict__ qg, const u16* __restrict__ kg,
    const u16* __restrict__ vg, u16* __restrict__ s2)
{
    __shared__ u16 ks[4096];    // K tile  [kv][d], XOR-swizzled, 8KB
    __shared__ u16 vts[4096];   // V^T tile [d][kv], XOR-swizzled, 8KB
    __shared__ u16 ssb[4096];   // per-wave S strips [q_local][kv], swizzled

    // XCD swizzle: physical blocks round-robin across 8 XCDs; map so all 8
    // n0-tiles of one (b,h) land on the SAME XCD (shared K/V -> L2 hits).
    const int id  = blockIdx.x;                 // 0..1023
    const int lid = (id & 7) * 128 + (id >> 3); // bijective (1024 % 8 == 0)
    const int bh  = lid >> 3;                   // b*H + h
    const int n0  = (lid & 7) * 64;
    const int b   = bh >> 3, hh = bh & 7;

    const int tid  = threadIdx.x;
    const int w    = tid >> 6;         // wave 0..3 -> q rows [16w,16w+16)
    const int lane = tid & 63;
    const int l15  = lane & 15, g = lane >> 4;

    // staging coords
    const int krow = tid >> 4;          // K: row (+16i), coalesced rows
    const int kcol = (tid & 15) * 4;
    const int vkv  = (tid & 15) * 4;    // V: 4x4 register-transpose block
    const int vd   = (tid >> 4) * 4;

    f32x4 vmem[4];  // LIF state; vmem[d0][r] <-> O[q=16w+4g+r][d=16*d0+l15]
    #pragma unroll
    for (int d0 = 0; d0 < 4; ++d0) vmem[d0] = {0.f, 0.f, 0.f, 0.f};

    #pragma unroll 1
    for (int t = 0; t < T_; ++t) {
        const size_t base = ((size_t)t * (B_ * H_) + bh) * (size_t)(N_ * D_);

        // Q fragments straight from global (each row used by exactly 1 wave)
        bf16x8 qa[2];
        qa[0] = *reinterpret_cast<const bf16x8*>(qg + base + (size_t)(n0 + 16 * w + l15) * D_ + 8 * g);
        qa[1] = *reinterpret_cast<const bf16x8*>(qg + base + (size_t)(n0 + 16 * w + l15) * D_ + 32 + 8 * g);

        f32x4 oacc[4];
        #pragma unroll
        for (int d0 = 0; d0 < 4; ++d0) oacc[d0] = {0.f, 0.f, 0.f, 0.f};

        #pragma unroll 1
        for (int jt = 0; jt < 8; ++jt) {
            const int m0 = jt * 64;
            // stage K tile (b64 swizzled writes, conflict-free)
            #pragma unroll
            for (int i = 0; i < 4; ++i) {
                const int row = krow + 16 * i;
                const ushort4 kv4 = *reinterpret_cast<const ushort4*>(
                    kg + base + (size_t)(m0 + row) * D_ + kcol);
                *reinterpret_cast<ushort4*>(&ks[SW(row, kcol)]) = kv4;
            }
            // stage V^T tile via 4x4 register transpose (b64 writes, 2-way free)
            {
                const ushort4 r0 = *reinterpret_cast<const ushort4*>(vg + base + (size_t)(m0 + vkv + 0) * D_ + vd);
                const ushort4 r1 = *reinterpret_cast<const ushort4*>(vg + base + (size_t)(m0 + vkv + 1) * D_ + vd);
                const ushort4 r2 = *reinterpret_cast<const ushort4*>(vg + base + (size_t)(m0 + vkv + 2) * D_ + vd);
                const ushort4 r3 = *reinterpret_cast<const ushort4*>(vg + base + (size_t)(m0 + vkv + 3) * D_ + vd);
                ushort4 wv;
                wv.x = r0.x; wv.y = r1.x; wv.z = r2.x; wv.w = r3.x;
                *reinterpret_cast<ushort4*>(&vts[SW(vd + 0, vkv)]) = wv;
                wv.x = r0.y; wv.y = r1.y; wv.z = r2.y; wv.w = r3.y;
                *reinterpret_cast<ushort4*>(&vts[SW(vd + 1, vkv)]) = wv;
                wv.x = r0.z; wv.y = r1.z; wv.z = r2.z; wv.w = r3.z;
                *reinterpret_cast<ushort4*>(&vts[SW(vd + 2, vkv)]) = wv;
                wv.x = r0.w; wv.y = r1.w; wv.z = r2.w; wv.w = r3.w;
                *reinterpret_cast<ushort4*>(&vts[SW(vd + 3, vkv)]) = wv;
            }
            __syncthreads();

            // QK^T -> wave-private S strip (16 x 64), scaled, bf16 (exact)
            #pragma unroll
            for (int kvt = 0; kvt < 4; ++kvt) {
                f32x4 acc = {0.f, 0.f, 0.f, 0.f};
                #pragma unroll
                for (int c = 0; c < 2; ++c) {
                    const bf16x8 kb = *reinterpret_cast<const bf16x8*>(
                        &ks[SW(16 * kvt + l15, 32 * c + 8 * g)]);
                    acc = __builtin_amdgcn_mfma_f32_16x16x32_bf16(qa[c], kb, acc, 0, 0, 0);
                }
                #pragma unroll
                for (int r = 0; r < 4; ++r)
                    ssb[w * 1024 + SW(4 * g + r, 16 * kvt + l15)] =
                        f2bf_exact(acc[r] * 0.125f);
            }

            // PV: O strip += S(16x64) * V(64x64). ssb is wave-private -> the
            // compiler's lgkmcnt ordering suffices, no barrier needed here.
            #pragma unroll
            for (int c = 0; c < 2; ++c) {
                const bf16x8 sa = *reinterpret_cast<const bf16x8*>(
                    &ssb[w * 1024 + SW(l15, 32 * c + 8 * g)]);
                #pragma unroll
                for (int d0 = 0; d0 < 4; ++d0) {
                    const bf16x8 vb = *reinterpret_cast<const bf16x8*>(
                        &vts[SW(16 * d0 + l15, 32 * c + 8 * g)]);
                    oacc[d0] = __builtin_amdgcn_mfma_f32_16x16x32_bf16(sa, vb, oacc[d0], 0, 0, 0);
                }
            }
            __syncthreads();   // before next tile overwrites ks/vts
        }

        // LIF (v_th = 0.5), exact; write bf16 spikes to s2 [T,B,N,C]
        #pragma unroll
        for (int d0 = 0; d0 < 4; ++d0) {
            #pragma unroll
            for (int r = 0; r < 4; ++r) {
                const float h = vmem[d0][r] + (oacc[d0][r] - vmem[d0][r]) * 0.5f;
                const bool sp = (h >= 0.5f);
                vmem[d0][r] = sp ? 0.f : h;
                const int n = n0 + 16 * w + 4 * g + r;
                const int c = hh * 64 + d0 * 16 + l15;
                s2[((size_t)t * BN_T + (size_t)b * N_ + n) * C_ + c] = sp ? 0x3F80 : 0;
            }
        }
    }
}

extern "C" void kernel_launch(void* const* d_in, const int* in_sizes, int n_in,
                              void* d_out, int out_size, void* d_ws, size_t ws_size,
                              hipStream_t stream)
{
    const float* x = (const float*)d_in[0];
    const float* W[4]  = {(const float*)d_in[1],  (const float*)d_in[7],  (const float*)d_in[13], (const float*)d_in[19]};
    const float* Bi[4] = {(const float*)d_in[2],  (const float*)d_in[8],  (const float*)d_in[14], (const float*)d_in[20]};
    const float* Ga[4] = {(const float*)d_in[3],  (const float*)d_in[9],  (const float*)d_in[15], (const float*)d_in[21]};
    const float* Be[4] = {(const float*)d_in[4],  (const float*)d_in[10], (const float*)d_in[16], (const float*)d_in[22]};
    const float* Mu[4] = {(const float*)d_in[5],  (const float*)d_in[11], (const float*)d_in[17], (const float*)d_in[23]};
    const float* Va[4] = {(const float*)d_in[6],  (const float*)d_in[12], (const float*)d_in[18], (const float*)d_in[24]};

    const size_t SPK = (size_t)T_ * B_ * N_ * C_;   // 16,777,216 elems
    u16* qb  = (u16*)d_ws;          // bf16 spikes [T,B,H,N,D]
    u16* kbf = qb + SPK;
    u16* vbf = kbf + SPK;
    u16* s2  = vbf + SPK;           // bf16 spikes [T,B,N,C]

    dim3 grid(C_ / 64, BN_T / 64), blk(256);
    k_linear_bn_lif<false, true><<<grid, blk, 0, stream>>>(x, W[0], Bi[0], Ga[0], Be[0], Mu[0], Va[0], qb);
    k_linear_bn_lif<false, true><<<grid, blk, 0, stream>>>(x, W[1], Bi[1], Ga[1], Be[1], Mu[1], Va[1], kbf);
    k_linear_bn_lif<false, true><<<grid, blk, 0, stream>>>(x, W[2], Bi[2], Ga[2], Be[2], Mu[2], Va[2], vbf);
    k_attn_mfma<<<dim3(1024), blk, 0, stream>>>(qb, kbf, vbf, s2);
    k_linear_bn_lif<true, false><<<grid, blk, 0, stream>>>(s2, W[3], Bi[3], Ga[3], Be[3], Mu[3], Va[3], d_out);
}

// Round 3
// 410.017 us; speedup vs baseline: 4.1595x; 2.5405x over previous
//
#include <hip/hip_runtime.h>
#include <hip/hip_bf16.h>
#include <hip/hip_fp16.h>
#include <cstddef>

#define T_ 4
#define B_ 16
#define N_ 512
#define C_ 512
#define H_ 8
#define D_ 64
#define BN_T (B_*N_)   // 8192

typedef unsigned short u16;
typedef __attribute__((ext_vector_type(8))) short bf16x8;       // 8 bf16
typedef __attribute__((ext_vector_type(8))) _Float16 f16x8;     // 8 fp16
typedef __attribute__((ext_vector_type(8))) unsigned short u16x8;
typedef __attribute__((ext_vector_type(4))) float f32x4;

__device__ __forceinline__ float bf2f(u16 u) {
    union { unsigned int i; float f; } x; x.i = ((unsigned int)u) << 16; return x.f;
}
__device__ __forceinline__ u16 f2bf_exact(float f) {
    union { float f; unsigned u; } x; x.f = f; return (u16)(x.u >> 16);
}
// 2-term exact fp16 split: f == h1 + h2/2048 + tail(<=2^-22|f|)
__device__ __forceinline__ void split2(float f, u16& h1, u16& h2) {
    const __half a = __float2half(f);                   // RNE
    const float r = (f - __half2float(a)) * 2048.0f;    // exact (Sterbenz + pow2)
    const __half b = __float2half(r);
    h1 = __half_as_ushort(a); h2 = __half_as_ushort(b);
}
// XOR swizzle, 16B granularity, for [128][32] fp16 tiles (row = 64B).
// Rows 0..7 land on 8 distinct 16B slots -> uniform 2 lanes/bank on b128 ops.
__device__ __forceinline__ int swz(int rr, int q) {
    return (rr << 6) + (((q ^ ((rr >> 1) & 3)) & 3) << 4);   // BYTE offset
}

// ---------------------------------------------------------------------------
// Weight split: w fp32 [512x512] -> w1, w2s fp16 (w2s scaled by 2048)
// ---------------------------------------------------------------------------
__global__ __launch_bounds__(256) void k_split_w(
    const float* __restrict__ w, u16* __restrict__ w1, u16* __restrict__ w2)
{
    const int i4 = blockIdx.x * 256 + threadIdx.x;   // 65536 float4s = 262144 f
    const float4 f = reinterpret_cast<const float4*>(w)[i4];
    ushort4 a, b;
    split2(f.x, a.x, b.x); split2(f.y, a.y, b.y);
    split2(f.z, a.z, b.z); split2(f.w, a.w, b.w);
    reinterpret_cast<ushort4*>(w1)[i4] = a;
    reinterpret_cast<ushort4*>(w2)[i4] = b;
}

// ---------------------------------------------------------------------------
// Split-fp16 MFMA Linear -> BN(eval) -> LIF over T=4.
// MODE 0: x fp32 in (split on the fly), LIF v_th=1.0, head-layout bf16 spikes.
// MODE 1: fp16 spike input (exact), LIF v_th=1.0, fp32 0/1 out (d_out).
// Block: 128 M-rows (32 bn x 4 t, t fastest) x 128 cols; 4 M-waves; K-step 32.
// LDS rows rr = bn_local*4 + t  ==> C-frag row 4*(l>>4)+r gives t == reg r,
// so the LIF recurrence runs across the 4 accumulator registers in-lane.
// y = accA + accBC/2048 + bias   (exact-split reconstruction)
// ---------------------------------------------------------------------------
template<int MODE>
__global__ __launch_bounds__(256, 2) void k_linear_mfma(
    const void* __restrict__ xin, const u16* __restrict__ w1g, const u16* __restrict__ w2g,
    const float* __restrict__ bias, const float* __restrict__ gamma,
    const float* __restrict__ beta, const float* __restrict__ mean,
    const float* __restrict__ var, void* __restrict__ outp)
{
    __shared__ u16 lds[16384];            // A1|A2|B1|B2, each [128][32] fp16
    u16* const A1 = lds;
    u16* const A2 = lds + 4096;
    u16* const B1 = lds + 8192;
    u16* const B2 = lds + 12288;

    // XCD swizzle: each XCD gets 32 consecutive mtiles with all 4 ntiles
    const int dd  = blockIdx.x;                    // 0..1023
    const int lid = (dd & 7) * 128 + (dd >> 3);    // bijective
    const int mt  = lid >> 2;                      // 0..255
    const int nt  = lid & 3;
    const int bn0 = mt * 32;
    const int c0  = nt * 128;

    const int tid = threadIdx.x;
    const int wv  = tid >> 6;
    const int l15 = tid & 15, g = (tid & 63) >> 4;

    const int srr = tid >> 1, shf = tid & 1;       // staging: row 0..127, k-half
    const int st  = srr & 3,  sbn = srr >> 2;      // A row -> (t, bn_local)

    f32x4 accA[2][8], accB[2][8];
    #pragma unroll
    for (int rt = 0; rt < 2; ++rt)
        #pragma unroll
        for (int ct = 0; ct < 8; ++ct) { accA[rt][ct] = {0,0,0,0}; accB[rt][ct] = {0,0,0,0}; }

    #pragma unroll 1
    for (int kb = 0; kb < 16; ++kb) {
        const int k0 = kb * 32;
        // ---- stage A (fp32 split on the fly, or exact fp16 spikes) ----
        const size_t arow = ((size_t)(st * BN_T + bn0 + sbn)) * C_ + k0 + shf * 16;
        if (MODE == 0) {
            const float* src = (const float*)xin + arow;
            float f[16];
            *reinterpret_cast<float4*>(f + 0)  = *reinterpret_cast<const float4*>(src + 0);
            *reinterpret_cast<float4*>(f + 4)  = *reinterpret_cast<const float4*>(src + 4);
            *reinterpret_cast<float4*>(f + 8)  = *reinterpret_cast<const float4*>(src + 8);
            *reinterpret_cast<float4*>(f + 12) = *reinterpret_cast<const float4*>(src + 12);
            #pragma unroll
            for (int j = 0; j < 2; ++j) {
                u16x8 p1, p2;
                #pragma unroll
                for (int e = 0; e < 8; ++e) { u16 h1, h2; split2(f[8*j+e], h1, h2); p1[e] = h1; p2[e] = h2; }
                const int q = 2 * shf + j;
                *reinterpret_cast<u16x8*>((char*)A1 + swz(srr, q)) = p1;
                *reinterpret_cast<u16x8*>((char*)A2 + swz(srr, q)) = p2;
            }
        } else {
            const u16* src = (const u16*)xin + arow;
            #pragma unroll
            for (int j = 0; j < 2; ++j) {
                const int q = 2 * shf + j;
                *reinterpret_cast<u16x8*>((char*)A1 + swz(srr, q)) =
                    *reinterpret_cast<const u16x8*>(src + 8 * j);
            }
        }
        // ---- stage B (pre-split fp16 weights, [c][k] row-major) ----
        {
            const size_t off = (size_t)(c0 + srr) * C_ + k0 + shf * 16;
            #pragma unroll
            for (int j = 0; j < 2; ++j) {
                const int q = 2 * shf + j;
                *reinterpret_cast<u16x8*>((char*)B1 + swz(srr, q)) =
                    *reinterpret_cast<const u16x8*>(w1g + off + 8 * j);
                *reinterpret_cast<u16x8*>((char*)B2 + swz(srr, q)) =
                    *reinterpret_cast<const u16x8*>(w2g + off + 8 * j);
            }
        }
        __syncthreads();
        // ---- compute ----
        f16x8 a1[2], a2[2];
        #pragma unroll
        for (int rt = 0; rt < 2; ++rt) {
            const int rr = wv * 32 + rt * 16 + l15;
            a1[rt] = *reinterpret_cast<const f16x8*>((const char*)A1 + swz(rr, g));
            if (MODE == 0)
                a2[rt] = *reinterpret_cast<const f16x8*>((const char*)A2 + swz(rr, g));
        }
        #pragma unroll
        for (int ct = 0; ct < 8; ++ct) {
            const int rr = ct * 16 + l15;
            const f16x8 b1 = *reinterpret_cast<const f16x8*>((const char*)B1 + swz(rr, g));
            const f16x8 b2 = *reinterpret_cast<const f16x8*>((const char*)B2 + swz(rr, g));
            #pragma unroll
            for (int rt = 0; rt < 2; ++rt) {
                accA[rt][ct] = __builtin_amdgcn_mfma_f32_16x16x32_f16(a1[rt], b1, accA[rt][ct], 0, 0, 0);
                if (MODE == 0) {
                    accB[rt][ct] = __builtin_amdgcn_mfma_f32_16x16x32_f16(a2[rt], b1, accB[rt][ct], 0, 0, 0);
                    accB[rt][ct] = __builtin_amdgcn_mfma_f32_16x16x32_f16(a1[rt], b2, accB[rt][ct], 0, 0, 0);
                } else {
                    accB[rt][ct] = __builtin_amdgcn_mfma_f32_16x16x32_f16(a1[rt], b2, accB[rt][ct], 0, 0, 0);
                }
            }
        }
        __syncthreads();
    }

    // ---- epilogue: reconstruct -> bias -> BN -> LIF(v_th=1) over reg r==t ----
    #pragma unroll
    for (int ct = 0; ct < 8; ++ct) {
        const int c = c0 + ct * 16 + l15;
        const float rs = 1.0f / sqrtf(var[c] + 1e-5f);
        const float ga = gamma[c], be = beta[c], mu = mean[c], bi = bias[c];
        #pragma unroll
        for (int rt = 0; rt < 2; ++rt) {
            const int bn = bn0 + wv * 8 + rt * 4 + g;
            float vm = 0.f;
            #pragma unroll
            for (int r = 0; r < 4; ++r) {
                const float y = accA[rt][ct][r] + accB[rt][ct][r] * (1.0f / 2048.0f) + bi;
                const float ybn = (y - mu) * rs * ga + be;
                const float h = vm + (ybn - vm) * 0.5f;
                const bool sp = (h >= 1.0f);
                vm = sp ? 0.f : h;
                if (MODE == 0) {
                    const int b = bn >> 9, n = bn & 511;
                    const int hh = c >> 6, d2 = c & 63;
                    ((u16*)outp)[((((size_t)r * B_ + b) * H_ + hh) * N_ + n) * D_ + d2] = sp ? 0x3F80 : 0;
                } else {
                    ((float*)outp)[((size_t)r * BN_T + bn) * C_ + c] = sp ? 1.0f : 0.0f;
                }
            }
        }
    }
}

// ---------------------------------------------------------------------------
// MFMA attention (verified round 2) — unchanged except s2 spikes now fp16.
// ---------------------------------------------------------------------------
__global__ __launch_bounds__(256) void k_attn_mfma(
    const u16* __restrict__ qg, const u16* __restrict__ kg,
    const u16* __restrict__ vg, u16* __restrict__ s2)
{
    __shared__ u16 ks[4096];
    __shared__ u16 vts[4096];
    __shared__ u16 ssb[4096];

    const int id  = blockIdx.x;
    const int lid = (id & 7) * 128 + (id >> 3);
    const int bh  = lid >> 3;
    const int n0  = (lid & 7) * 64;
    const int b   = bh >> 3, hh = bh & 7;

    const int tid  = threadIdx.x;
    const int w    = tid >> 6;
    const int lane = tid & 63;
    const int l15  = lane & 15, g = lane >> 4;

    const int krow = tid >> 4;
    const int kcol = (tid & 15) * 4;
    const int vkv  = (tid & 15) * 4;
    const int vd   = (tid >> 4) * 4;

    f32x4 vmem[4];
    #pragma unroll
    for (int d0 = 0; d0 < 4; ++d0) vmem[d0] = {0.f, 0.f, 0.f, 0.f};

    #pragma unroll 1
    for (int t = 0; t < T_; ++t) {
        const size_t base = ((size_t)t * (B_ * H_) + bh) * (size_t)(N_ * D_);

        bf16x8 qa[2];
        qa[0] = *reinterpret_cast<const bf16x8*>(qg + base + (size_t)(n0 + 16 * w + l15) * D_ + 8 * g);
        qa[1] = *reinterpret_cast<const bf16x8*>(qg + base + (size_t)(n0 + 16 * w + l15) * D_ + 32 + 8 * g);

        f32x4 oacc[4];
        #pragma unroll
        for (int d0 = 0; d0 < 4; ++d0) oacc[d0] = {0.f, 0.f, 0.f, 0.f};

        #pragma unroll 1
        for (int jt = 0; jt < 8; ++jt) {
            const int m0 = jt * 64;
            #pragma unroll
            for (int i = 0; i < 4; ++i) {
                const int row = krow + 16 * i;
                const ushort4 kv4 = *reinterpret_cast<const ushort4*>(
                    kg + base + (size_t)(m0 + row) * D_ + kcol);
                *reinterpret_cast<ushort4*>(&ks[(row << 6) + (kcol ^ ((row & 7) << 3))]) = kv4;
            }
            {
                const ushort4 r0 = *reinterpret_cast<const ushort4*>(vg + base + (size_t)(m0 + vkv + 0) * D_ + vd);
                const ushort4 r1 = *reinterpret_cast<const ushort4*>(vg + base + (size_t)(m0 + vkv + 1) * D_ + vd);
                const ushort4 r2 = *reinterpret_cast<const ushort4*>(vg + base + (size_t)(m0 + vkv + 2) * D_ + vd);
                const ushort4 r3 = *reinterpret_cast<const ushort4*>(vg + base + (size_t)(m0 + vkv + 3) * D_ + vd);
                ushort4 wv4;
                wv4.x = r0.x; wv4.y = r1.x; wv4.z = r2.x; wv4.w = r3.x;
                *reinterpret_cast<ushort4*>(&vts[((vd + 0) << 6) + (vkv ^ (((vd + 0) & 7) << 3))]) = wv4;
                wv4.x = r0.y; wv4.y = r1.y; wv4.z = r2.y; wv4.w = r3.y;
                *reinterpret_cast<ushort4*>(&vts[((vd + 1) << 6) + (vkv ^ (((vd + 1) & 7) << 3))]) = wv4;
                wv4.x = r0.z; wv4.y = r1.z; wv4.z = r2.z; wv4.w = r3.z;
                *reinterpret_cast<ushort4*>(&vts[((vd + 2) << 6) + (vkv ^ (((vd + 2) & 7) << 3))]) = wv4;
                wv4.x = r0.w; wv4.y = r1.w; wv4.z = r2.w; wv4.w = r3.w;
                *reinterpret_cast<ushort4*>(&vts[((vd + 3) << 6) + (vkv ^ (((vd + 3) & 7) << 3))]) = wv4;
            }
            __syncthreads();

            #pragma unroll
            for (int kvt = 0; kvt < 4; ++kvt) {
                f32x4 acc = {0.f, 0.f, 0.f, 0.f};
                #pragma unroll
                for (int c = 0; c < 2; ++c) {
                    const int row = 16 * kvt + l15;
                    const bf16x8 kb = *reinterpret_cast<const bf16x8*>(
                        &ks[(row << 6) + ((32 * c + 8 * g) ^ ((row & 7) << 3))]);
                    acc = __builtin_amdgcn_mfma_f32_16x16x32_bf16(qa[c], kb, acc, 0, 0, 0);
                }
                #pragma unroll
                for (int r = 0; r < 4; ++r) {
                    const int row = 4 * g + r;
                    ssb[w * 1024 + (row << 6) + ((16 * kvt + l15) ^ ((row & 7) << 3))] =
                        f2bf_exact(acc[r] * 0.125f);
                }
            }

            #pragma unroll
            for (int c = 0; c < 2; ++c) {
                const int row = l15;
                const bf16x8 sa = *reinterpret_cast<const bf16x8*>(
                    &ssb[w * 1024 + (row << 6) + ((32 * c + 8 * g) ^ ((row & 7) << 3))]);
                #pragma unroll
                for (int d0 = 0; d0 < 4; ++d0) {
                    const int vr = 16 * d0 + l15;
                    const bf16x8 vb = *reinterpret_cast<const bf16x8*>(
                        &vts[(vr << 6) + ((32 * c + 8 * g) ^ ((vr & 7) << 3))]);
                    oacc[d0] = __builtin_amdgcn_mfma_f32_16x16x32_bf16(sa, vb, oacc[d0], 0, 0, 0);
                }
            }
            __syncthreads();
        }

        #pragma unroll
        for (int d0 = 0; d0 < 4; ++d0) {
            #pragma unroll
            for (int r = 0; r < 4; ++r) {
                const float h = vmem[d0][r] + (oacc[d0][r] - vmem[d0][r]) * 0.5f;
                const bool sp = (h >= 0.5f);
                vmem[d0][r] = sp ? 0.f : h;
                const int n = n0 + 16 * w + 4 * g + r;
                const int c = hh * 64 + d0 * 16 + l15;
                s2[((size_t)t * BN_T + (size_t)b * N_ + n) * C_ + c] = sp ? 0x3C00 : 0;  // fp16 1.0
            }
        }
    }
}

extern "C" void kernel_launch(void* const* d_in, const int* in_sizes, int n_in,
                              void* d_out, int out_size, void* d_ws, size_t ws_size,
                              hipStream_t stream)
{
    const float* x = (const float*)d_in[0];
    const float* W[4]  = {(const float*)d_in[1],  (const float*)d_in[7],  (const float*)d_in[13], (const float*)d_in[19]};
    const float* Bi[4] = {(const float*)d_in[2],  (const float*)d_in[8],  (const float*)d_in[14], (const float*)d_in[20]};
    const float* Ga[4] = {(const float*)d_in[3],  (const float*)d_in[9],  (const float*)d_in[15], (const float*)d_in[21]};
    const float* Be[4] = {(const float*)d_in[4],  (const float*)d_in[10], (const float*)d_in[16], (const float*)d_in[22]};
    const float* Mu[4] = {(const float*)d_in[5],  (const float*)d_in[11], (const float*)d_in[17], (const float*)d_in[23]};
    const float* Va[4] = {(const float*)d_in[6],  (const float*)d_in[12], (const float*)d_in[18], (const float*)d_in[24]};

    const size_t SPK = (size_t)T_ * B_ * N_ * C_;   // 16,777,216
    const size_t WSZ = (size_t)C_ * C_;             // 262,144
    u16* qb  = (u16*)d_ws;          // bf16 spikes [T,B,H,N,D]
    u16* kbf = qb + SPK;
    u16* vbf = kbf + SPK;
    u16* s2  = vbf + SPK;           // fp16 spikes [T,B,N,C] (written by attn)
    // Weight splits live in regions that are dead at the time of use:
    //   wq/wk/wv splits -> s2 region (s2 not written until attn runs)
    //   wp split        -> qb region (qb dead after attn)
    u16* wsp[4][2] = {
        {s2 + 0 * WSZ, s2 + 1 * WSZ},
        {s2 + 2 * WSZ, s2 + 3 * WSZ},
        {s2 + 4 * WSZ, s2 + 5 * WSZ},
        {qb + 0 * WSZ, qb + 1 * WSZ},
    };

    dim3 blk(256);
    for (int i = 0; i < 3; ++i)
        k_split_w<<<256, blk, 0, stream>>>(W[i], wsp[i][0], wsp[i][1]);
    k_linear_mfma<0><<<1024, blk, 0, stream>>>(x, wsp[0][0], wsp[0][1], Bi[0], Ga[0], Be[0], Mu[0], Va[0], qb);
    k_linear_mfma<0><<<1024, blk, 0, stream>>>(x, wsp[1][0], wsp[1][1], Bi[1], Ga[1], Be[1], Mu[1], Va[1], kbf);
    k_linear_mfma<0><<<1024, blk, 0, stream>>>(x, wsp[2][0], wsp[2][1], Bi[2], Ga[2], Be[2], Mu[2], Va[2], vbf);
    k_attn_mfma<<<1024, blk, 0, stream>>>(qb, kbf, vbf, s2);
    k_split_w<<<256, blk, 0, stream>>>(W[3], wsp[3][0], wsp[3][1]);
    k_linear_mfma<1><<<1024, blk, 0, stream>>>(s2, wsp[3][0], wsp[3][1], Bi[3], Ga[3], Be[3], Mu[3], Va[3], d_out);
}

// Round 4
// 322.322 us; speedup vs baseline: 5.2912x; 1.2721x over previous
//
#include <hip/hip_runtime.h>
#include <hip/hip_bf16.h>
#include <hip/hip_fp16.h>
#include <cstddef>
#include <cstdint>

#define T_ 4
#define B_ 16
#define N_ 512
#define C_ 512
#define H_ 8
#define D_ 64
#define BN_T (B_*N_)   // 8192

typedef unsigned short u16;
typedef __attribute__((ext_vector_type(8))) short bf16x8;       // 8 bf16
typedef __attribute__((ext_vector_type(8))) _Float16 f16x8;     // 8 fp16
typedef __attribute__((ext_vector_type(8))) unsigned short u16x8;
typedef __attribute__((ext_vector_type(4))) float f32x4;

__device__ __forceinline__ u16 f2bf_exact(float f) {
    union { float f; unsigned u; } x; x.f = f; return (u16)(x.u >> 16);
}
// 2-term exact fp16 split: f == h1 + h2/2048 + tail(<=2^-22|f|)
__device__ __forceinline__ void split2(float f, u16& h1, u16& h2) {
    const __half a = __float2half(f);                   // RNE
    const float r = (f - __half2float(a)) * 2048.0f;    // exact (Sterbenz + pow2)
    const __half b = __float2half(r);
    h1 = __half_as_ushort(a); h2 = __half_as_ushort(b);
}
// XOR swizzle, 16B granularity, BYTE offset into a [128][32] fp16 tile (64B rows)
__device__ __forceinline__ int swz(int rr, int q) {
    return (rr << 6) + (((q ^ ((rr >> 1) & 3)) & 3) << 4);
}
// attention LDS swizzle (element index into [64][64] u16 tiles)
__device__ __forceinline__ int SW(int row, int col) {
    return (row << 6) + (col ^ ((row & 7) << 3));
}
// async global->LDS, 16B per lane (dest = uniform base + lane*16)
__device__ __forceinline__ void gload16(const void* g, void* l) {
    __builtin_amdgcn_global_load_lds(
        (const __attribute__((address_space(1))) unsigned int*)g,
        (__attribute__((address_space(3))) unsigned int*)l, 16, 0, 0);
}

// ---------------------------------------------------------------------------
// x fp32 [T,BN,C] -> tile-major pre-swizzled fp16 splits x1t, x2t.
// Tile (mt,kb) holds A-rows rr=4*bn_local+t (bn = mt*32+bn_local), k=kb*32..+32,
// stored exactly as the GEMM wants it in LDS (swz 16B slots). 8KB per tile.
// ---------------------------------------------------------------------------
__global__ __launch_bounds__(256) void k_split_x(
    const float* __restrict__ x, u16* __restrict__ x1t, u16* __restrict__ x2t)
{
    const int tile = blockIdx.x;            // mt*16 + kb  (4096 tiles)
    const int mt = tile >> 4, kb = tile & 15;
    const int tid = threadIdx.x;
    const int rr = tid >> 1, kh = tid & 1;
    const int t = rr & 3, bn = mt * 32 + (rr >> 2);
    const float* src = x + ((size_t)t * BN_T + bn) * C_ + kb * 32 + kh * 16;
    float f[16];
    *reinterpret_cast<float4*>(f + 0)  = *reinterpret_cast<const float4*>(src + 0);
    *reinterpret_cast<float4*>(f + 4)  = *reinterpret_cast<const float4*>(src + 4);
    *reinterpret_cast<float4*>(f + 8)  = *reinterpret_cast<const float4*>(src + 8);
    *reinterpret_cast<float4*>(f + 12) = *reinterpret_cast<const float4*>(src + 12);
    char* d1 = (char*)(x1t + ((size_t)tile << 12));
    char* d2 = (char*)(x2t + ((size_t)tile << 12));
    #pragma unroll
    for (int j = 0; j < 2; ++j) {
        u16x8 p1, p2;
        #pragma unroll
        for (int e = 0; e < 8; ++e) { u16 h1, h2; split2(f[8*j+e], h1, h2); p1[e] = h1; p2[e] = h2; }
        const int q = 2 * kh + j;
        *reinterpret_cast<u16x8*>(d1 + swz(rr, q)) = p1;
        *reinterpret_cast<u16x8*>(d2 + swz(rr, q)) = p2;
    }
}

// w fp32 [512][512] -> tile-major pre-swizzled fp16 splits (tile = (nt,kb), row rr = c_local)
__global__ __launch_bounds__(256) void k_split_w(
    const float* __restrict__ w, u16* __restrict__ w1t, u16* __restrict__ w2t)
{
    const int tile = blockIdx.x;            // nt*16 + kb  (64 tiles)
    const int nt = tile >> 4, kb = tile & 15;
    const int tid = threadIdx.x;
    const int rr = tid >> 1, kh = tid & 1;
    const int c = nt * 128 + rr;
    const float* src = w + (size_t)c * C_ + kb * 32 + kh * 16;
    float f[16];
    *reinterpret_cast<float4*>(f + 0)  = *reinterpret_cast<const float4*>(src + 0);
    *reinterpret_cast<float4*>(f + 4)  = *reinterpret_cast<const float4*>(src + 4);
    *reinterpret_cast<float4*>(f + 8)  = *reinterpret_cast<const float4*>(src + 8);
    *reinterpret_cast<float4*>(f + 12) = *reinterpret_cast<const float4*>(src + 12);
    char* d1 = (char*)(w1t + ((size_t)tile << 12));
    char* d2 = (char*)(w2t + ((size_t)tile << 12));
    #pragma unroll
    for (int j = 0; j < 2; ++j) {
        u16x8 p1, p2;
        #pragma unroll
        for (int e = 0; e < 8; ++e) { u16 h1, h2; split2(f[8*j+e], h1, h2); p1[e] = h1; p2[e] = h2; }
        const int q = 2 * kh + j;
        *reinterpret_cast<u16x8*>(d1 + swz(rr, q)) = p1;
        *reinterpret_cast<u16x8*>(d2 + swz(rr, q)) = p2;
    }
}

// ---------------------------------------------------------------------------
// Split-fp16 MFMA Linear -> BN(eval) -> LIF over T=4, m97-structure:
// global_load_lds DMA staging of pre-swizzled tiles, double-buffered LDS,
// stage(k+1) issued before compute(k). Numerics identical to round 3.
// MODE 0: A = x1t,x2t (3 MFMA terms), head-layout bf16 spike out.
// MODE 1: A = s2t spikes fp16 exact (2 terms), fp32 0/1 out (d_out).
// ---------------------------------------------------------------------------
template<int MODE>
__global__ __launch_bounds__(256, 2) void k_linear_mfma(
    const u16* __restrict__ a1t, const u16* __restrict__ a2t,
    const u16* __restrict__ w1t, const u16* __restrict__ w2t,
    const float* __restrict__ bias, const float* __restrict__ gamma,
    const float* __restrict__ beta, const float* __restrict__ mean,
    const float* __restrict__ var, void* __restrict__ outp)
{
    __shared__ u16 lds[2][4][4096];   // [buf][A1,A2,B1,B2][8KB tile]

    const int dd  = blockIdx.x;                    // 0..1023
    const int lid = (dd & 7) * 128 + (dd >> 3);    // XCD swizzle (bijective)
    const int mt  = lid >> 2;                      // 0..255
    const int nt  = lid & 3;
    const int bn0 = mt * 32;
    const int c0  = nt * 128;

    const int tid = threadIdx.x;
    const int wv  = tid >> 6, lane = tid & 63;
    const int l15 = tid & 15, g = (tid & 63) >> 4;
    const int go  = wv * 2048 + lane * 16;   // per-lane byte offset in tile
    const int lo  = wv * 2048;               // wave-uniform LDS byte offset

    f32x4 accA[2][8], accB[2][8];
    #pragma unroll
    for (int rt = 0; rt < 2; ++rt)
        #pragma unroll
        for (int ct = 0; ct < 8; ++ct) { accA[rt][ct] = {0,0,0,0}; accB[rt][ct] = {0,0,0,0}; }

    const size_t abase = (size_t)mt * 16, bbase = (size_t)nt * 16;

    auto stage = [&](int buf, int kb) {
        char* L = (char*)&lds[buf][0][0];
        const char* ga1 = (const char*)(a1t + ((abase + kb) << 12)) + go;
        const char* gb1 = (const char*)(w1t + ((bbase + kb) << 12)) + go;
        const char* gb2 = (const char*)(w2t + ((bbase + kb) << 12)) + go;
        gload16(ga1,        L + lo);
        gload16(ga1 + 1024, L + lo + 1024);
        if (MODE == 0) {
            const char* ga2 = (const char*)(a2t + ((abase + kb) << 12)) + go;
            gload16(ga2,        L + 8192 + lo);
            gload16(ga2 + 1024, L + 8192 + lo + 1024);
        }
        gload16(gb1,        L + 16384 + lo);
        gload16(gb1 + 1024, L + 16384 + lo + 1024);
        gload16(gb2,        L + 24576 + lo);
        gload16(gb2 + 1024, L + 24576 + lo + 1024);
    };

    stage(0, 0);
    __syncthreads();

    #pragma unroll 1
    for (int kb = 0; kb < 16; ++kb) {
        const int buf = kb & 1;
        if (kb < 15) stage(buf ^ 1, kb + 1);       // async, flies under MFMAs
        const char* L = (const char*)&lds[buf][0][0];
        f16x8 a1[2], a2[2];
        #pragma unroll
        for (int rt = 0; rt < 2; ++rt) {
            const int rr = wv * 32 + rt * 16 + l15;
            a1[rt] = *reinterpret_cast<const f16x8*>(L + swz(rr, g));
            if (MODE == 0)
                a2[rt] = *reinterpret_cast<const f16x8*>(L + 8192 + swz(rr, g));
        }
        #pragma unroll
        for (int ct = 0; ct < 8; ++ct) {
            const int rr2 = ct * 16 + l15;
            const f16x8 b1 = *reinterpret_cast<const f16x8*>(L + 16384 + swz(rr2, g));
            const f16x8 b2 = *reinterpret_cast<const f16x8*>(L + 24576 + swz(rr2, g));
            #pragma unroll
            for (int rt = 0; rt < 2; ++rt) {
                accA[rt][ct] = __builtin_amdgcn_mfma_f32_16x16x32_f16(a1[rt], b1, accA[rt][ct], 0, 0, 0);
                if (MODE == 0)
                    accB[rt][ct] = __builtin_amdgcn_mfma_f32_16x16x32_f16(a2[rt], b1, accB[rt][ct], 0, 0, 0);
                accB[rt][ct] = __builtin_amdgcn_mfma_f32_16x16x32_f16(a1[rt], b2, accB[rt][ct], 0, 0, 0);
            }
        }
        __syncthreads();   // drains this wave's stage loads + everyone's reads
    }

    // epilogue: reconstruct -> bias -> BN -> LIF(v_th=1) over reg r==t
    #pragma unroll
    for (int ct = 0; ct < 8; ++ct) {
        const int c = c0 + ct * 16 + l15;
        const float rs = 1.0f / sqrtf(var[c] + 1e-5f);
        const float ga = gamma[c], be = beta[c], mu = mean[c], bi = bias[c];
        #pragma unroll
        for (int rt = 0; rt < 2; ++rt) {
            const int bn = bn0 + wv * 8 + rt * 4 + g;
            float vm = 0.f;
            #pragma unroll
            for (int r = 0; r < 4; ++r) {
                const float y = accA[rt][ct][r] + accB[rt][ct][r] * (1.0f / 2048.0f) + bi;
                const float ybn = (y - mu) * rs * ga + be;
                const float h = vm + (ybn - vm) * 0.5f;
                const bool sp = (h >= 1.0f);
                vm = sp ? 0.f : h;
                if (MODE == 0) {
                    const int b = bn >> 9, n = bn & 511;
                    const int hh = c >> 6, d2 = c & 63;
                    ((u16*)outp)[((((size_t)r * B_ + b) * H_ + hh) * N_ + n) * D_ + d2] = sp ? 0x3F80 : 0;
                } else {
                    ((float*)outp)[((size_t)r * BN_T + bn) * C_ + c] = sp ? 1.0f : 0.0f;
                }
            }
        }
    }
}

// ---------------------------------------------------------------------------
// MFMA attention + LIF(0.5), flattened (t,jt) loop with register prefetch of
// next tile's K/V/Q (T14). S path identical to verified round 3. Output s2
// written in tile-major swizzled fp16 layout for k_linear_mfma<1>.
// ---------------------------------------------------------------------------
__global__ __launch_bounds__(256) void k_attn_mfma(
    const u16* __restrict__ qg, const u16* __restrict__ kg,
    const u16* __restrict__ vg, u16* __restrict__ s2t)
{
    __shared__ u16 ks[4096];
    __shared__ u16 vts[4096];
    __shared__ u16 ssb[4096];

    const int id  = blockIdx.x;
    const int lid = (id & 7) * 128 + (id >> 3);
    const int bh  = lid >> 3;
    const int n0  = (lid & 7) * 64;
    const int b   = bh >> 3, hh = bh & 7;

    const int tid  = threadIdx.x;
    const int w    = tid >> 6, lane = tid & 63;
    const int l15  = lane & 15, g = lane >> 4;
    const int krow = tid >> 4, kcol = (tid & 15) * 4;
    const int vkv  = (tid & 15) * 4, vd = (tid >> 4) * 4;

    f32x4 vmem[4], oacc[4];
    #pragma unroll
    for (int d0 = 0; d0 < 4; ++d0) { vmem[d0] = {0,0,0,0}; oacc[d0] = {0,0,0,0}; }

    ushort4 kpre[4], vpre[4];
    bf16x8 qpre[2], qa[2];

    auto prefetch = [&](int it2) {
        const int t2 = it2 >> 3, m0 = (it2 & 7) * 64;
        const size_t base2 = ((size_t)t2 * (B_ * H_) + bh) * (size_t)(N_ * D_);
        #pragma unroll
        for (int i = 0; i < 4; ++i)
            kpre[i] = *reinterpret_cast<const ushort4*>(kg + base2 + (size_t)(m0 + krow + 16 * i) * D_ + kcol);
        #pragma unroll
        for (int i = 0; i < 4; ++i)
            vpre[i] = *reinterpret_cast<const ushort4*>(vg + base2 + (size_t)(m0 + vkv + i) * D_ + vd);
        if ((it2 & 7) == 0) {
            qpre[0] = *reinterpret_cast<const bf16x8*>(qg + base2 + (size_t)(n0 + 16 * w + l15) * D_ + 8 * g);
            qpre[1] = *reinterpret_cast<const bf16x8*>(qg + base2 + (size_t)(n0 + 16 * w + l15) * D_ + 32 + 8 * g);
        }
    };

    prefetch(0);

    #pragma unroll 1
    for (int it = 0; it < 32; ++it) {
        const int t = it >> 3, jt = it & 7;
        if (jt == 0) { qa[0] = qpre[0]; qa[1] = qpre[1]; }

        // write prefetched tile into LDS
        #pragma unroll
        for (int i = 0; i < 4; ++i) {
            const int row = krow + 16 * i;
            *reinterpret_cast<ushort4*>(&ks[SW(row, kcol)]) = kpre[i];
        }
        #pragma unroll
        for (int j = 0; j < 4; ++j) {
            ushort4 wv4;
            wv4.x = (&vpre[0].x)[j]; wv4.y = (&vpre[1].x)[j];
            wv4.z = (&vpre[2].x)[j]; wv4.w = (&vpre[3].x)[j];
            *reinterpret_cast<ushort4*>(&vts[SW(vd + j, vkv)]) = wv4;
        }
        __syncthreads();
        if (it < 31) prefetch(it + 1);   // flies under the MFMAs below

        // QK^T -> wave-private S strip (16 x 64), scaled, bf16 (exact)
        #pragma unroll
        for (int kvt = 0; kvt < 4; ++kvt) {
            f32x4 acc = {0.f, 0.f, 0.f, 0.f};
            #pragma unroll
            for (int c = 0; c < 2; ++c) {
                const bf16x8 kb = *reinterpret_cast<const bf16x8*>(
                    &ks[SW(16 * kvt + l15, 32 * c + 8 * g)]);
                acc = __builtin_amdgcn_mfma_f32_16x16x32_bf16(qa[c], kb, acc, 0, 0, 0);
            }
            #pragma unroll
            for (int r = 0; r < 4; ++r)
                ssb[w * 1024 + SW(4 * g + r, 16 * kvt + l15)] = f2bf_exact(acc[r] * 0.125f);
        }
        // PV (ssb wave-private; lgkmcnt ordering suffices)
        #pragma unroll
        for (int c = 0; c < 2; ++c) {
            const bf16x8 sa = *reinterpret_cast<const bf16x8*>(
                &ssb[w * 1024 + SW(l15, 32 * c + 8 * g)]);
            #pragma unroll
            for (int d0 = 0; d0 < 4; ++d0) {
                const bf16x8 vb = *reinterpret_cast<const bf16x8*>(
                    &vts[SW(16 * d0 + l15, 32 * c + 8 * g)]);
                oacc[d0] = __builtin_amdgcn_mfma_f32_16x16x32_bf16(sa, vb, oacc[d0], 0, 0, 0);
            }
        }
        __syncthreads();

        if (jt == 7) {
            // LIF (v_th=0.5), exact; write fp16 spikes in tiled layout
            #pragma unroll
            for (int d0 = 0; d0 < 4; ++d0) {
                const int c = hh * 64 + d0 * 16 + l15;
                const int kb2 = c >> 5, kq = (c >> 3) & 3, e = c & 7;
                #pragma unroll
                for (int r = 0; r < 4; ++r) {
                    const float h = vmem[d0][r] + (oacc[d0][r] - vmem[d0][r]) * 0.5f;
                    const bool sp = (h >= 0.5f);
                    vmem[d0][r] = sp ? 0.f : h;
                    const int n = n0 + 16 * w + 4 * g + r;
                    const int bn = b * 512 + n;
                    const int mt2 = bn >> 5;
                    const int rr2 = (bn & 31) * 4 + t;
                    const size_t off = (((size_t)mt2 * 16 + kb2) << 13) + (rr2 << 6)
                                     + (((kq ^ ((rr2 >> 1) & 3)) & 3) << 4) + (e << 1);
                    *(u16*)((char*)s2t + off) = sp ? 0x3C00 : 0;   // fp16 1.0
                }
                oacc[d0] = {0.f, 0.f, 0.f, 0.f};
            }
        }
    }
}

extern "C" void kernel_launch(void* const* d_in, const int* in_sizes, int n_in,
                              void* d_out, int out_size, void* d_ws, size_t ws_size,
                              hipStream_t stream)
{
    const float* x = (const float*)d_in[0];
    const float* W[4]  = {(const float*)d_in[1],  (const float*)d_in[7],  (const float*)d_in[13], (const float*)d_in[19]};
    const float* Bi[4] = {(const float*)d_in[2],  (const float*)d_in[8],  (const float*)d_in[14], (const float*)d_in[20]};
    const float* Ga[4] = {(const float*)d_in[3],  (const float*)d_in[9],  (const float*)d_in[15], (const float*)d_in[21]};
    const float* Be[4] = {(const float*)d_in[4],  (const float*)d_in[10], (const float*)d_in[16], (const float*)d_in[22]};
    const float* Mu[4] = {(const float*)d_in[5],  (const float*)d_in[11], (const float*)d_in[17], (const float*)d_in[23]};
    const float* Va[4] = {(const float*)d_in[6],  (const float*)d_in[12], (const float*)d_in[18], (const float*)d_in[24]};

    const size_t SPK = (size_t)T_ * B_ * N_ * C_;   // 16,777,216
    const size_t WSZ = (size_t)C_ * C_;             // 262,144
    u16* qb  = (u16*)d_ws;          // bf16 spikes [T,B,H,N,D]
    u16* kbf = qb + SPK;
    u16* vbf = kbf + SPK;
    u16* x1t = vbf + SPK;           // tiled x1; reused as s2t after linears
    u16* x2t = x1t + SPK;           // tiled x2
    u16* wt  = x2t + SPK;           // 4 weights x 2 splits x WSZ
    u16* s2t = x1t;                 // attn output overlays x1t (dead by then)

    dim3 blk(256);
    k_split_x<<<4096, blk, 0, stream>>>(x, x1t, x2t);
    for (int i = 0; i < 4; ++i)
        k_split_w<<<64, blk, 0, stream>>>(W[i], wt + (2*i) * WSZ, wt + (2*i+1) * WSZ);

    k_linear_mfma<0><<<1024, blk, 0, stream>>>(x1t, x2t, wt + 0*WSZ, wt + 1*WSZ, Bi[0], Ga[0], Be[0], Mu[0], Va[0], qb);
    k_linear_mfma<0><<<1024, blk, 0, stream>>>(x1t, x2t, wt + 2*WSZ, wt + 3*WSZ, Bi[1], Ga[1], Be[1], Mu[1], Va[1], kbf);
    k_linear_mfma<0><<<1024, blk, 0, stream>>>(x1t, x2t, wt + 4*WSZ, wt + 5*WSZ, Bi[2], Ga[2], Be[2], Mu[2], Va[2], vbf);
    k_attn_mfma<<<1024, blk, 0, stream>>>(qb, kbf, vbf, s2t);
    k_linear_mfma<1><<<1024, blk, 0, stream>>>(s2t, x2t, wt + 6*WSZ, wt + 7*WSZ, Bi[3], Ga[3], Be[3], Mu[3], Va[3], d_out);
}